// Round 1
// baseline (1475.239 us; speedup 1.0000x reference)
//
#include <hip/hip_runtime.h>
#include <math.h>

// Problem constants (match reference)
#define DIN 128
#define NH 4
#define NC 32
#define HC 128          // NH*NC
static constexpr float NEG_SLOPE = 0.2f;

__device__ __forceinline__ float leaky(float x) { return x > 0.f ? x : NEG_SLOPE * x; }

// ---------------------------------------------------------------------------
// K0: init deg/wsum to 0, out to bias
__global__ void k_init(float* __restrict__ deg, float* __restrict__ wsum,
                       float* __restrict__ out, const float* __restrict__ bias, int n) {
  int i = blockIdx.x * blockDim.x + threadIdx.x;
  if (i < n) { deg[i] = 0.f; wsum[i] = 0.f; }
  if (i < n * HC) out[i] = bias[i & (HC - 1)];
}

// ---------------------------------------------------------------------------
// K1: h = x @ W  (128x128), plus a_src[n][h], a_dst[n][h]
// 256 threads = 2 rows per iteration, 128 threads per row. W staged in LDS (64KB).
__global__ __launch_bounds__(256) void k_proj(
    const float* __restrict__ x, const float* __restrict__ W,
    const float* __restrict__ att_s, const float* __restrict__ att_d,
    float* __restrict__ h, float* __restrict__ a_src, float* __restrict__ a_dst, int n) {
  __shared__ float Wl[DIN * HC];  // 64 KiB
  int tid = threadIdx.x;
  for (int i = tid; i < DIN * HC; i += 256) Wl[i] = W[i];
  __syncthreads();

  int j = tid & 127;           // output column 0..127
  int sub = tid >> 7;          // 0/1 : which row of the pair
  int hh = j >> 5;             // head
  int lane32 = j & 31;
  float as = att_s[j], ad = att_d[j];

  for (int base = blockIdx.x * 2; base < n; base += gridDim.x * 2) {
    int row = base + sub;
    if (row >= n) break;
    const float* xr = x + (size_t)row * DIN;
    float acc = 0.f;
#pragma unroll 16
    for (int k = 0; k < DIN; ++k) acc = fmaf(xr[k], Wl[k * HC + j], acc);
    h[(size_t)row * HC + j] = acc;
    float rs = acc * as, rd = acc * ad;
#pragma unroll
    for (int m = 16; m >= 1; m >>= 1) {
      rs += __shfl_xor(rs, m, 64);
      rd += __shfl_xor(rd, m, 64);
    }
    if (lane32 == 0) { a_src[row * NH + hh] = rs; a_dst[row * NH + hh] = rd; }
  }
}

// ---------------------------------------------------------------------------
// K2: deg + weighted sum per dst node
__global__ void k_degw(const int* __restrict__ dst, const float* __restrict__ w,
                       float* __restrict__ deg, float* __restrict__ wsum, int E) {
  int i = blockIdx.x * blockDim.x + threadIdx.x;
  if (i < E) {
    int d = dst[i];
    atomicAdd(&deg[d], 1.f);
    atomicAdd(&wsum[d], w[i]);
  }
}

// ---------------------------------------------------------------------------
// K3: self-loop logits; denom initialized to ex_self
__global__ void k_self(const float* __restrict__ a_src, const float* __restrict__ a_dst,
                       const float* __restrict__ deg, const float* __restrict__ wsum,
                       float* __restrict__ ex_self, float* __restrict__ denom, int n) {
  int i = blockIdx.x * blockDim.x + threadIdx.x;
  if (i < n * NH) {
    int nd = i >> 2;
    float dg = deg[nd];
    float lw = dg > 0.f ? wsum[nd] / dg : 1.f;
    float a = leaky(a_src[i] + a_dst[i]) + log2f(lw);
    float ex = expf(a);
    ex_self[i] = ex;
    denom[i] = ex;
  }
}

// ---------------------------------------------------------------------------
// K4: accumulate exp(alpha) per (dst, head). No max-subtraction needed:
// logits bounded (|a|<~8, log2(w) in [-4.33,0]) -> exp safe in fp32.
__global__ void k_edge_denom(const int* __restrict__ ei, const float* __restrict__ w,
                             const float* __restrict__ a_src, const float* __restrict__ a_dst,
                             float* __restrict__ denom, int E) {
  int e = blockIdx.x * blockDim.x + threadIdx.x;
  if (e >= E) return;
  int s = ei[e], d = ei[E + e];
  float lw = log2f(w[e]);
  const float4 as = *reinterpret_cast<const float4*>(a_src + s * NH);
  const float4 ad = *reinterpret_cast<const float4*>(a_dst + d * NH);
  atomicAdd(&denom[d * NH + 0], expf(leaky(as.x + ad.x) + lw));
  atomicAdd(&denom[d * NH + 1], expf(leaky(as.y + ad.y) + lw));
  atomicAdd(&denom[d * NH + 2], expf(leaky(as.z + ad.z) + lw));
  atomicAdd(&denom[d * NH + 3], expf(leaky(as.w + ad.w) + lw));
}

// ---------------------------------------------------------------------------
// K5: scatter-aggregate messages. One thread per (edge, channel).
// Wave = 64 consecutive channels of one edge -> coalesced gather + coalesced atomics.
__global__ void k_agg(const int* __restrict__ ei, const float* __restrict__ w,
                      const float* __restrict__ a_src, const float* __restrict__ a_dst,
                      const float* __restrict__ denom, const float* __restrict__ h,
                      float* __restrict__ out, int E) {
  int gid = blockIdx.x * blockDim.x + threadIdx.x;   // E*128 = 204.8M < 2^31
  int e = gid >> 7;
  if (e >= E) return;
  int j = gid & 127;
  int hh = j >> 5;
  int s = ei[e], d = ei[E + e];
  float a = a_src[s * NH + hh] + a_dst[d * NH + hh];
  float r = expf(leaky(a) + log2f(w[e])) / denom[d * NH + hh];
  atomicAdd(&out[(size_t)d * HC + j], r * h[(size_t)s * HC + j]);
}

// ---------------------------------------------------------------------------
// K6: add self-loop contribution (single writer per element -> plain RMW)
__global__ void k_selfagg(const float* __restrict__ ex_self, const float* __restrict__ denom,
                          const float* __restrict__ h, float* __restrict__ out, int n) {
  int gid = blockIdx.x * blockDim.x + threadIdx.x;
  if (gid >= n * HC) return;
  int nd = gid >> 7;
  int j = gid & 127;
  int hh = j >> 5;
  float r = ex_self[nd * NH + hh] / denom[nd * NH + hh];
  out[gid] += r * h[gid];
}

// ---------------------------------------------------------------------------
extern "C" void kernel_launch(void* const* d_in, const int* in_sizes, int n_in,
                              void* d_out, int out_size, void* d_ws, size_t ws_size,
                              hipStream_t stream) {
  const float* x        = (const float*)d_in[0];
  const int*   ei       = (const int*)d_in[1];     // [2][E]: src row 0, dst row 1
  const float* eattr    = (const float*)d_in[2];
  const float* W        = (const float*)d_in[3];
  const float* att_src  = (const float*)d_in[4];
  const float* att_dst  = (const float*)d_in[5];
  const float* bias     = (const float*)d_in[6];
  float* out = (float*)d_out;

  const int n = in_sizes[0] / DIN;
  const int E = in_sizes[2];

  // workspace layout (floats)
  float* ws      = (float*)d_ws;
  float* h       = ws;                         // n*128
  float* a_src   = h + (size_t)n * HC;         // n*4
  float* a_dst   = a_src + (size_t)n * NH;     // n*4
  float* deg     = a_dst + (size_t)n * NH;     // n
  float* wsum    = deg + n;                    // n
  float* denom   = wsum + n;                   // n*4
  float* ex_self = denom + (size_t)n * NH;     // n*4

  const int* dst_idx = ei + E;

  k_init<<<(n * HC + 255) / 256, 256, 0, stream>>>(deg, wsum, out, bias, n);
  k_proj<<<2048, 256, 0, stream>>>(x, W, att_src, att_dst, h, a_src, a_dst, n);
  k_degw<<<(E + 255) / 256, 256, 0, stream>>>(dst_idx, eattr, deg, wsum, E);
  k_self<<<(n * NH + 255) / 256, 256, 0, stream>>>(a_src, a_dst, deg, wsum, ex_self, denom, n);
  k_edge_denom<<<(E + 255) / 256, 256, 0, stream>>>(ei, eattr, a_src, a_dst, denom, E);
  {
    long long tot = (long long)E * HC;
    int blocks = (int)((tot + 255) / 256);
    k_agg<<<blocks, 256, 0, stream>>>(ei, eattr, a_src, a_dst, denom, h, out, E);
  }
  k_selfagg<<<(n * HC + 255) / 256, 256, 0, stream>>>(ex_self, denom, h, out, n);
}

// Round 2
// 845.854 us; speedup vs baseline: 1.7441x; 1.7441x over previous
//
#include <hip/hip_runtime.h>
#include <math.h>

#define DIN 128
#define NH 4
#define NC 32
#define HC 128
static constexpr float NEG_SLOPE = 0.2f;

__device__ __forceinline__ float leaky(float x) { return x > 0.f ? x : NEG_SLOPE * x; }

// ---------------------------------------------------------------------------
// K1: h = x @ W (128x128), a_src[n][H], a_dst[n][H]. W staged in LDS.
__global__ __launch_bounds__(256) void k_proj(
    const float* __restrict__ x, const float* __restrict__ W,
    const float* __restrict__ att_s, const float* __restrict__ att_d,
    float* __restrict__ h, float* __restrict__ a_src, float* __restrict__ a_dst, int n) {
  __shared__ float Wl[DIN * HC];  // 64 KiB
  int tid = threadIdx.x;
  for (int i = tid; i < DIN * HC; i += 256) Wl[i] = W[i];
  __syncthreads();

  int j = tid & 127;
  int sub = tid >> 7;
  int hh = j >> 5;
  int lane32 = j & 31;
  float as = att_s[j], ad = att_d[j];

  for (int base = blockIdx.x * 2; base < n; base += gridDim.x * 2) {
    int row = base + sub;
    if (row >= n) break;
    const float* xr = x + (size_t)row * DIN;
    float acc = 0.f;
#pragma unroll 16
    for (int k = 0; k < DIN; ++k) acc = fmaf(xr[k], Wl[k * HC + j], acc);
    h[(size_t)row * HC + j] = acc;
    float rs = acc * as, rd = acc * ad;
#pragma unroll
    for (int m = 16; m >= 1; m >>= 1) {
      rs += __shfl_xor(rs, m, 64);
      rd += __shfl_xor(rd, m, 64);
    }
    if (lane32 == 0) { a_src[row * NH + hh] = rs; a_dst[row * NH + hh] = rd; }
  }
}

// ---------------------------------------------------------------------------
// CSR build: count -> scan -> scatter
__global__ void k_zero(int* __restrict__ cnt, int n) {
  int i = blockIdx.x * blockDim.x + threadIdx.x;
  if (i < n) cnt[i] = 0;
}

__global__ void k_count(const int* __restrict__ dst, int* __restrict__ cnt, int E) {
  int e = blockIdx.x * blockDim.x + threadIdx.x;
  if (e < E) atomicAdd(&cnt[dst[e]], 1);
}

// scan1: each block scans a 1024-chunk of cnt into off (exclusive within chunk),
// writes chunk total to bsum
__global__ __launch_bounds__(256) void k_scan1(const int* __restrict__ cnt,
                                               int* __restrict__ off,
                                               int* __restrict__ bsum, int n) {
  __shared__ int lds[256];
  int b = blockIdx.x, t = threadIdx.x;
  int base = b * 1024 + t * 4;
  int v0 = 0, v1 = 0, v2 = 0, v3 = 0;
  if (base + 0 < n) v0 = cnt[base + 0];
  if (base + 1 < n) v1 = cnt[base + 1];
  if (base + 2 < n) v2 = cnt[base + 2];
  if (base + 3 < n) v3 = cnt[base + 3];
  int s = v0 + v1 + v2 + v3;
  lds[t] = s;
  __syncthreads();
  for (int ofs = 1; ofs < 256; ofs <<= 1) {
    int x = (t >= ofs) ? lds[t - ofs] : 0;
    __syncthreads();
    lds[t] += x;
    __syncthreads();
  }
  int run = (t > 0) ? lds[t - 1] : 0;
  if (t == 255) bsum[b] = lds[255];
  if (base + 0 < n) { off[base + 0] = run; run += v0; }
  if (base + 1 < n) { off[base + 1] = run; run += v1; }
  if (base + 2 < n) { off[base + 2] = run; run += v2; }
  if (base + 3 < n) { off[base + 3] = run; run += v3; }
}

// scan2: exclusive scan of bsum (nb <= 256) in one block
__global__ __launch_bounds__(256) void k_scan2(int* __restrict__ bsum, int nb) {
  __shared__ int lds[256];
  int t = threadIdx.x;
  lds[t] = (t < nb) ? bsum[t] : 0;
  __syncthreads();
  for (int ofs = 1; ofs < 256; ofs <<= 1) {
    int x = (t >= ofs) ? lds[t - ofs] : 0;
    __syncthreads();
    lds[t] += x;
    __syncthreads();
  }
  int excl = (t > 0) ? lds[t - 1] : 0;
  if (t < nb) bsum[t] = excl;
}

// scan3: add chunk offsets; duplicate into cursor; set off[n]=E
__global__ void k_scan3(int* __restrict__ off, const int* __restrict__ bsum,
                        int* __restrict__ cursor, int n, int E) {
  int i = blockIdx.x * blockDim.x + threadIdx.x;
  if (i < n) {
    int v = off[i] + bsum[i >> 10];
    off[i] = v;
    cursor[i] = v;
  }
  if (i == 0) off[n] = E;
}

// scatter edges into dst-sorted order: edges[p] = {src, bits(w)}
__global__ void k_scatter(const int* __restrict__ ei, const float* __restrict__ w,
                          int* __restrict__ cursor, int2* __restrict__ edges, int E) {
  int e = blockIdx.x * blockDim.x + threadIdx.x;
  if (e >= E) return;
  int s = ei[e], d = ei[E + e];
  int p = atomicAdd(&cursor[d], 1);
  edges[p] = make_int2(s, __float_as_int(w[e]));
}

// ---------------------------------------------------------------------------
// K5: gather-aggregate. 128 threads per dst node (2 nodes / 256-block).
// Single pass: numerator, denominator, wsum in registers; self-loop at end;
// exactly one store per output element. No float atomics anywhere.
__global__ __launch_bounds__(256) void k_gather(
    const int2* __restrict__ edges, const int* __restrict__ off,
    const float* __restrict__ a_src, const float* __restrict__ a_dst,
    const float* __restrict__ h, const float* __restrict__ bias,
    float* __restrict__ out, int n) {
  int node = blockIdx.x * 2 + (threadIdx.x >> 7);
  if (node >= n) return;
  int j = threadIdx.x & 127;
  int hh = j >> 5;
  float ad = a_dst[node * NH + hh];
  int beg = off[node], end = off[node + 1];
  float acc = 0.f, den = 0.f, wsum = 0.f;
  for (int k = beg; k < end; ++k) {
    int2 ew = edges[k];
    int s = ew.x;
    float w = __int_as_float(ew.y);
    float as = a_src[s * NH + hh];
    float ex = expf(leaky(as + ad) + log2f(w));
    den += ex;
    wsum += w;
    acc = fmaf(ex, h[(size_t)s * HC + j], acc);
  }
  int deg = end - beg;
  float lw = deg > 0 ? wsum / (float)deg : 1.f;
  float exs = expf(leaky(a_src[node * NH + hh] + ad) + log2f(lw));
  den += exs;
  acc = fmaf(exs, h[(size_t)node * HC + j], acc);
  out[(size_t)node * HC + j] = acc / den + bias[j];
}

// ---------------------------------------------------------------------------
extern "C" void kernel_launch(void* const* d_in, const int* in_sizes, int n_in,
                              void* d_out, int out_size, void* d_ws, size_t ws_size,
                              hipStream_t stream) {
  const float* x       = (const float*)d_in[0];
  const int*   ei      = (const int*)d_in[1];   // [2][E]
  const float* eattr   = (const float*)d_in[2];
  const float* W       = (const float*)d_in[3];
  const float* att_src = (const float*)d_in[4];
  const float* att_dst = (const float*)d_in[5];
  const float* bias    = (const float*)d_in[6];
  float* out = (float*)d_out;

  const int n = in_sizes[0] / DIN;
  const int E = in_sizes[2];

  // workspace layout
  float* h     = (float*)d_ws;                       // n*HC floats (even count -> 8B align ok)
  int2*  edges = (int2*)(h + (size_t)n * HC);        // E int2
  float* a_src = (float*)(edges + E);                // n*NH
  float* a_dst = a_src + (size_t)n * NH;             // n*NH
  int*   off   = (int*)(a_dst + (size_t)n * NH);     // n+1
  int*   cnt   = off + n + 1;                        // n
  int*   cursor= cnt + n;                            // n
  int*   bsum  = cursor + n;                         // <=256

  const int* dst_idx = ei + E;
  int nb = (n + 1023) / 1024;

  k_proj<<<2048, 256, 0, stream>>>(x, W, att_src, att_dst, h, a_src, a_dst, n);
  k_zero<<<(n + 255) / 256, 256, 0, stream>>>(cnt, n);
  k_count<<<(E + 255) / 256, 256, 0, stream>>>(dst_idx, cnt, E);
  k_scan1<<<nb, 256, 0, stream>>>(cnt, off, bsum, n);
  k_scan2<<<1, 256, 0, stream>>>(bsum, nb);
  k_scan3<<<(n + 255) / 256, 256, 0, stream>>>(off, bsum, cursor, n, E);
  k_scatter<<<(E + 255) / 256, 256, 0, stream>>>(ei, eattr, cursor, edges, E);
  k_gather<<<(n + 1) / 2, 256, 0, stream>>>(edges, off, a_src, a_dst, h, bias, out, n);
}